// Round 5
// baseline (502.700 us; speedup 1.0000x reference)
//
#include <hip/hip_runtime.h>
#include <hip/hip_bf16.h>

typedef unsigned short u16;
typedef unsigned int u32;
typedef __bf16 bf16x8 __attribute__((ext_vector_type(8)));
typedef float f32x4 __attribute__((ext_vector_type(4)));
typedef unsigned int u32x4 __attribute__((ext_vector_type(4)));

// ---------------- constants ----------------
#define BATCH 8
#define SEQ   2048
#define DIM   1024
#define M_TOT (BATCH * SEQ)      // 16384
#define N_QKV (3 * DIM)          // 3072

// workspace layout (bytes) — peak 201,326,592 (192 MiB)
#define OFF_QKV  ((size_t)0)
#define OFF_VT   ((size_t)100663296)
#define OFF_C    ((size_t)134217728)
#define OFF_XB   OFF_C
#define OFF_WT   (OFF_C + (size_t)33554432)
#define OFF_S    OFF_C

__device__ __forceinline__ u16 f32_to_bf16(float f) {
    u32 u = __builtin_bit_cast(u32, f);
    u = (u + 0x7fffu + ((u >> 16) & 1u)) >> 16;
    return (u16)u;
}

__device__ __forceinline__ float bf16_to_f32(u16 h) {
    u32 u = ((u32)h) << 16;
    return __builtin_bit_cast(float, u);
}

__device__ __forceinline__ bf16x8 lds_load8(const u16* p) {
    return __builtin_bit_cast(bf16x8, *(const u32x4*)p);
}

// ---- BK=64 tile staging, 128-thread (2-wave) blocks ----
// 128x64 bf16 tile = 1024 16B-chunks; 128 threads x 8 issues.
// Chunk slot s holds data (row = s>>3, kg = (s&7) ^ (row&7)) — XOR swizzle,
// verified conflict-free in R3/R4 (SQ_LDS_BANK_CONFLICT == 0).
__device__ __forceinline__ void stage_tile64(const u16* gA, size_t lda, u16* ldsA, int tid) {
    int wv = tid >> 6;
#pragma unroll
    for (int iss = 0; iss < 8; ++iss) {
        int s = iss * 128 + tid;            // chunk slot 0..1023
        int row = s >> 3;                   // 8 chunks per 64-wide row
        int kg = (s & 7) ^ (row & 7);       // swizzled k-group for this slot
        const u16* gp = gA + (size_t)row * lda + (kg << 3);
        u16* lp = ldsA + (size_t)(iss * 128 + wv * 64) * 8;  // wave-uniform base
        __builtin_amdgcn_global_load_lds((const __attribute__((address_space(1))) void*)gp,
                                         (__attribute__((address_space(3))) void*)lp,
                                         16, 0, 0);
    }
}

// 2-wave MFMA step: wave wv computes rows [wv*64, wv*64+64) x all 128 cols
// of the 128x128 C tile — 4x8 fragments of 16x16x32 per K=32 sub-step.
// 12 ds_read_b128 feed 32 MFMAs (vs 8:16 in the 4-wave layout) -> 42 FLOP/B
// of LDS traffic instead of 32 — attacks the LDS-BW bound seen in R4.
// (row & 7) == (lane & 7) for all fragment rows, so the swizzle term is a
// per-lane constant — zero extra inner-loop VALU.
__device__ __forceinline__ void mfma_step2w(const u16* ldsA, const u16* ldsB, int tid,
                                            f32x4 acc[4][8]) {
    int lane = tid & 63;
    int wv = tid >> 6;
    int wr = wv * 64;
    int lrow = lane & 15, kgl = lane >> 4;
    int xr = lrow & 7;
#pragma unroll
    for (int ks = 0; ks < 2; ++ks) {
        int off = ((ks * 4 + kgl) ^ xr) << 3;
        bf16x8 a[4], b[8];
#pragma unroll
        for (int i = 0; i < 4; ++i)
            a[i] = lds_load8(&ldsA[(wr + i * 16 + lrow) * 64 + off]);
#pragma unroll
        for (int j = 0; j < 8; ++j)
            b[j] = lds_load8(&ldsB[(j * 16 + lrow) * 64 + off]);
#pragma unroll
        for (int i = 0; i < 4; ++i)
#pragma unroll
            for (int j = 0; j < 8; ++j)
                acc[i][j] = __builtin_amdgcn_mfma_f32_16x16x32_bf16(a[i], b[j], acc[i][j], 0, 0, 0);
    }
}

// ---------------- kernel 1: prep = cast x (fp32->bf16) + transpose-cast W ----------------
// blocks [0, 768): transpose Wq/Wk/Wv 64x64 tiles; blocks [768, ...): cast x.
__global__ __launch_bounds__(256) void prep_kernel(const float* __restrict__ x,
                                                   const float* __restrict__ wq,
                                                   const float* __restrict__ wk,
                                                   const float* __restrict__ wv,
                                                   u16* __restrict__ xb,
                                                   u16* __restrict__ wt) {
    __shared__ __align__(16) u16 tile[64][80];
    int blk = blockIdx.x;
    if (blk >= 768) {
        size_t g = (size_t)(blk - 768) * 256 + threadIdx.x;   // group of 4 elems
        f32x4 v = ((const f32x4*)x)[g];
        u16 o[4] = {f32_to_bf16(v.x), f32_to_bf16(v.y), f32_to_bf16(v.z), f32_to_bf16(v.w)};
        *(unsigned long long*)(xb + g * 4) = *(const unsigned long long*)o;
        return;
    }
    int z = blk >> 8;            // 0..2 : which W
    int rem = blk & 255;         // 0..255 : 16x16 tile grid
    int kt = rem >> 4, nt2 = rem & 15;
    const float* w = z == 0 ? wq : (z == 1 ? wk : wv);
    int k0 = kt * 64, n0 = nt2 * 64;
    for (int g = threadIdx.x; g < 1024; g += 256) {
        int r = g >> 4, c = (g & 15) << 2;
        f32x4 v = *(const f32x4*)(w + (size_t)(k0 + r) * 1024 + n0 + c);
        tile[r][c + 0] = f32_to_bf16(v.x);
        tile[r][c + 1] = f32_to_bf16(v.y);
        tile[r][c + 2] = f32_to_bf16(v.z);
        tile[r][c + 3] = f32_to_bf16(v.w);
    }
    __syncthreads();
    u16* out = wt + (size_t)z * 1024 * 1024;
    for (int g = threadIdx.x; g < 512; g += 256) {
        int nr = g >> 3, kc = (g & 7) << 3;
        __align__(16) u16 tmp[8];
#pragma unroll
        for (int i = 0; i < 8; ++i) tmp[i] = tile[kc + i][nr];
        *(u32x4*)(out + (size_t)(n0 + nr) * 1024 + k0 + kc) = *(const u32x4*)tmp;
    }
}

// ---------------- kernel 2: QKV GEMM (128-thread blocks) ----------------
__global__ __launch_bounds__(128) void gemm_qkv_kernel(const u16* __restrict__ xb,
                                                       const u16* __restrict__ wt,
                                                       u16* __restrict__ qkv) {
    __shared__ __align__(16) u16 ldsA[128 * 64];
    __shared__ __align__(16) u16 ldsB[128 * 64];
    int nt = blockIdx.x, mt = blockIdx.y;
    const u16* A = xb + (size_t)mt * 128 * 1024;
    const u16* B = wt + (size_t)nt * 128 * 1024;
    int tid = threadIdx.x;
    f32x4 acc[4][8] = {};
    for (int kt = 0; kt < 16; ++kt) {
        __syncthreads();
        stage_tile64(A + kt * 64, 1024, ldsA, tid);
        stage_tile64(B + kt * 64, 1024, ldsB, tid);
        __syncthreads();
        mfma_step2w(ldsA, ldsB, tid, acc);
    }
    int lane = tid & 63, wv = tid >> 6;
    int wr = wv * 64;
    int r0 = (lane >> 4) * 4, c0 = lane & 15;
    size_t mbase = (size_t)mt * 128;
    int nbase = nt * 128;
#pragma unroll
    for (int i = 0; i < 4; ++i)
#pragma unroll
        for (int j = 0; j < 8; ++j) {
            int col = nbase + j * 16 + c0;
            float scale = (col < 1024) ? 0.03125f : 1.0f;  // fold 1/sqrt(1024) into Q
#pragma unroll
            for (int r = 0; r < 4; ++r) {
                int row = wr + i * 16 + r0 + r;
                qkv[(mbase + row) * (size_t)N_QKV + col] = f32_to_bf16(acc[i][j][r] * scale);
            }
        }
}

// ---------------- kernel 3: transpose V -> Vt [b][d][m] ----------------
__global__ __launch_bounds__(256) void transpose_v_kernel(const u16* __restrict__ qkv,
                                                          u16* __restrict__ vt) {
    __shared__ __align__(16) u16 tile[64][80];
    int m0 = blockIdx.x * 64, d0 = blockIdx.y * 64, b = blockIdx.z;
    const u16* src = qkv + (size_t)b * SEQ * N_QKV + 2048;  // V columns
    for (int g = threadIdx.x; g < 512; g += 256) {
        int r = g >> 3, c = (g & 7) << 3;
        *(u32x4*)&tile[r][c] = *(const u32x4*)(src + (size_t)(m0 + r) * N_QKV + d0 + c);
    }
    __syncthreads();
    u16* dst = vt + (size_t)b * DIM * SEQ;
    for (int g = threadIdx.x; g < 512; g += 256) {
        int dr = g >> 3, mc = (g & 7) << 3;
        __align__(16) u16 tmp[8];
#pragma unroll
        for (int i = 0; i < 8; ++i) tmp[i] = tile[mc + i][dr];
        *(u32x4*)(dst + (size_t)(d0 + dr) * SEQ + m0 + mc) = *(const u32x4*)tmp;
    }
}

// ---------------- kernel 4: S = Q . K^T, triangular grid, bf16 output ----------------
__global__ __launch_bounds__(128) void gemm_scores_kernel(const u16* __restrict__ qkv,
                                                          u16* __restrict__ S) {
    int t = blockIdx.x;      // 0..135 triangular index
    int b = blockIdx.y;
    int ntile = (int)((sqrtf(8.0f * (float)t + 1.0f) - 1.0f) * 0.5f);
    while ((ntile + 1) * (ntile + 2) / 2 <= t) ++ntile;
    while (ntile * (ntile + 1) / 2 > t) --ntile;
    int mtile = t - ntile * (ntile + 1) / 2;   // 0 <= mtile <= ntile
    __shared__ __align__(16) u16 ldsA[128 * 64];
    __shared__ __align__(16) u16 ldsB[128 * 64];
    const u16* A = qkv + (size_t)b * SEQ * N_QKV + (size_t)ntile * 128 * N_QKV;        // Q rows
    const u16* B = qkv + (size_t)b * SEQ * N_QKV + (size_t)mtile * 128 * N_QKV + 1024; // K rows
    int tid = threadIdx.x;
    f32x4 acc[4][8] = {};
    for (int kt = 0; kt < 16; ++kt) {
        __syncthreads();
        stage_tile64(A + kt * 64, N_QKV, ldsA, tid);
        stage_tile64(B + kt * 64, N_QKV, ldsB, tid);
        __syncthreads();
        mfma_step2w(ldsA, ldsB, tid, acc);
    }
    u16* out = S + (size_t)b * SEQ * SEQ + (size_t)ntile * 128 * SEQ + (size_t)mtile * 128;
    int lane = tid & 63, wv = tid >> 6;
    int wr = wv * 64;
    int r0 = (lane >> 4) * 4, c0 = lane & 15;
#pragma unroll
    for (int i = 0; i < 4; ++i)
#pragma unroll
        for (int j = 0; j < 8; ++j) {
            int col = j * 16 + c0;
#pragma unroll
            for (int r = 0; r < 4; ++r) {
                int row = wr + i * 16 + r0 + r;
                out[(size_t)row * SEQ + col] = f32_to_bf16(acc[i][j][r]);
            }
        }
}

// ---------------- kernel 5: row softmax over bf16 S, in-place, register-resident ----
__global__ __launch_bounds__(256) void softmax_kernel(u16* __restrict__ SP) {
    int gr = blockIdx.x;
    int n = gr & 2047;
    u16* s = SP + (size_t)gr * SEQ;
    __shared__ float red[4];
    int t = threadIdx.x;
    int base = t << 3;
    int len = n + 1;
    float v[8];
    float lmax = -3.0e38f;
    if (base < len) {
        u32x4 raw = *(const u32x4*)(s + base);
        const u16* h = (const u16*)&raw;
#pragma unroll
        for (int i = 0; i < 8; ++i) {
            v[i] = (base + i < len) ? bf16_to_f32(h[i]) : -3.0e38f;
            lmax = fmaxf(lmax, v[i]);
        }
    } else {
#pragma unroll
        for (int i = 0; i < 8; ++i) v[i] = -3.0e38f;
    }
#pragma unroll
    for (int off = 32; off; off >>= 1) lmax = fmaxf(lmax, __shfl_xor(lmax, off, 64));
    if ((t & 63) == 0) red[t >> 6] = lmax;
    __syncthreads();
    float gmax = fmaxf(fmaxf(red[0], red[1]), fmaxf(red[2], red[3]));
    __syncthreads();   // everyone has gmax before red is reused
    float lsum = 0.f;
#pragma unroll
    for (int i = 0; i < 8; ++i) {
        float e = __expf(v[i] - gmax);   // masked lanes -> exp(-huge) = 0
        v[i] = e;
        lsum += e;
    }
#pragma unroll
    for (int off = 32; off; off >>= 1) lsum += __shfl_xor(lsum, off, 64);
    if ((t & 63) == 0) red[t >> 6] = lsum;
    __syncthreads();
    float inv = 1.0f / (red[0] + red[1] + red[2] + red[3]);
    __align__(16) u16 o[8];
#pragma unroll
    for (int i = 0; i < 8; ++i) o[i] = f32_to_bf16(v[i] * inv);  // masked lanes write 0
    *(u32x4*)(s + base) = *(const u32x4*)o;
}

// ---------------- kernel 6: O = P . V (via Vt), causal K truncation ----------------
__global__ __launch_bounds__(128) void gemm_out_kernel(const u16* __restrict__ P,
                                                       const u16* __restrict__ vt,
                                                       float* __restrict__ O) {
    __shared__ __align__(16) u16 ldsA[128 * 64];
    __shared__ __align__(16) u16 ldsB[128 * 64];
    int dt = blockIdx.x, b = blockIdx.z;
    int ntile = (SEQ / 128 - 1) - blockIdx.y;   // longest blocks first
    const u16* A = P + (size_t)b * SEQ * SEQ + (size_t)ntile * 128 * SEQ;
    const u16* B = vt + (size_t)b * DIM * SEQ + (size_t)dt * 128 * SEQ;
    int tid = threadIdx.x;
    f32x4 acc[4][8] = {};
    int kTiles = ntile * 2 + 2;  // keys beyond n0+127 have P == 0 (BK=64 units)
    for (int kt = 0; kt < kTiles; ++kt) {
        __syncthreads();
        stage_tile64(A + kt * 64, SEQ, ldsA, tid);
        stage_tile64(B + kt * 64, SEQ, ldsB, tid);
        __syncthreads();
        mfma_step2w(ldsA, ldsB, tid, acc);
    }
    float* out = O + (size_t)b * SEQ * DIM + (size_t)ntile * 128 * DIM + (size_t)dt * 128;
    int lane = tid & 63, wv = tid >> 6;
    int wr = wv * 64;
    int r0 = (lane >> 4) * 4, c0 = lane & 15;
#pragma unroll
    for (int i = 0; i < 4; ++i)
#pragma unroll
        for (int j = 0; j < 8; ++j) {
            int col = j * 16 + c0;
#pragma unroll
            for (int r = 0; r < 4; ++r) {
                int row = wr + i * 16 + r0 + r;
                out[(size_t)row * DIM + col] = acc[i][j][r];
            }
        }
}

extern "C" void kernel_launch(void* const* d_in, const int* in_sizes, int n_in,
                              void* d_out, int out_size, void* d_ws, size_t ws_size,
                              hipStream_t stream) {
    const float* x = (const float*)d_in[0];
    const float* wq = (const float*)d_in[1];
    const float* wk = (const float*)d_in[2];
    const float* wv = (const float*)d_in[3];
    char* ws = (char*)d_ws;
    u16* qkv = (u16*)(ws + OFF_QKV);
    u16* vt = (u16*)(ws + OFF_VT);
    u16* xb = (u16*)(ws + OFF_XB);
    u16* wt = (u16*)(ws + OFF_WT);
    u16* S = (u16*)(ws + OFF_S);   // aliases xb/wt region (dead by then)
    float* O = (float*)d_out;

    prep_kernel<<<768 + M_TOT * DIM / 4 / 256, 256, 0, stream>>>(x, wq, wk, wv, xb, wt);
    gemm_qkv_kernel<<<dim3(N_QKV / 128, M_TOT / 128), 128, 0, stream>>>(xb, wt, qkv);
    transpose_v_kernel<<<dim3(SEQ / 64, DIM / 64, BATCH), 256, 0, stream>>>(qkv, vt);
    gemm_scores_kernel<<<dim3(136, BATCH), 128, 0, stream>>>(qkv, S);
    softmax_kernel<<<BATCH * SEQ, 256, 0, stream>>>(S);
    gemm_out_kernel<<<dim3(DIM / 128, SEQ / 128, BATCH), 128, 0, stream>>>(S, vt, O);
}

// Round 6
// 399.716 us; speedup vs baseline: 1.2576x; 1.2576x over previous
//
#include <hip/hip_runtime.h>
#include <hip/hip_bf16.h>

typedef unsigned short u16;
typedef unsigned int u32;
typedef __bf16 bf16x8 __attribute__((ext_vector_type(8)));
typedef float f32x4 __attribute__((ext_vector_type(4)));
typedef unsigned int u32x4 __attribute__((ext_vector_type(4)));

// ---------------- constants ----------------
#define BATCH 8
#define SEQ   2048
#define DIM   1024
#define M_TOT (BATCH * SEQ)      // 16384
#define N_QKV (3 * DIM)          // 3072

// workspace layout (bytes) — peak 201,326,592 (192 MiB)
#define OFF_QKV  ((size_t)0)
#define OFF_VT   ((size_t)100663296)
#define OFF_C    ((size_t)134217728)
#define OFF_XB   OFF_C
#define OFF_WT   (OFF_C + (size_t)33554432)
#define OFF_S    OFF_C

__device__ __forceinline__ u16 f32_to_bf16(float f) {
    u32 u = __builtin_bit_cast(u32, f);
    u = (u + 0x7fffu + ((u >> 16) & 1u)) >> 16;
    return (u16)u;
}

__device__ __forceinline__ float bf16_to_f32(u16 h) {
    u32 u = ((u32)h) << 16;
    return __builtin_bit_cast(float, u);
}

__device__ __forceinline__ bf16x8 lds_load8(const u16* p) {
    return __builtin_bit_cast(bf16x8, *(const u32x4*)p);
}

// ---- BK=64 tile staging, 256-thread (4-wave) blocks — R4-verified config ----
// 128x64 bf16 tile = 1024 16B-chunks; 256 threads x 4 issues.
// Chunk slot s holds data (row = s>>3, kg = (s&7) ^ (row&7)) — XOR swizzle,
// verified conflict-free in R3/R4 (SQ_LDS_BANK_CONFLICT == 0).
__device__ __forceinline__ void stage_tile64(const u16* gA, size_t lda, u16* ldsA, int tid) {
    int wv = tid >> 6;
#pragma unroll
    for (int iss = 0; iss < 4; ++iss) {
        int s = iss * 256 + tid;            // chunk slot 0..1023
        int row = s >> 3;                   // 8 chunks per 64-wide row
        int kg = (s & 7) ^ (row & 7);       // swizzled k-group for this slot
        const u16* gp = gA + (size_t)row * lda + (kg << 3);
        u16* lp = ldsA + (size_t)(iss * 256 + wv * 64) * 8;  // wave-uniform base
        __builtin_amdgcn_global_load_lds((const __attribute__((address_space(1))) void*)gp,
                                         (__attribute__((address_space(3))) void*)lp,
                                         16, 0, 0);
    }
}

// Two K=32 sub-steps over a 128x64 LDS tile: 4x4 fragments of 16x16x32 per
// sub-step, per-wave 64x64 of a 128x128 C tile (2x2 wave grid).
// R5 lesson: bigger per-wave tiles (acc[4][8]) blow the register budget and
// collapse occupancy — keep acc[4][4] (60 VGPR + 64 AGPR = 124 <= 128).
__device__ __forceinline__ void mfma_step64(const u16* ldsA, const u16* ldsB, int tid,
                                            f32x4 acc[4][4]) {
    int lane = tid & 63;
    int wv = tid >> 6;
    int wr = (wv >> 1) * 64, wc = (wv & 1) * 64;
    int lrow = lane & 15, kgl = lane >> 4;
    int xr = lrow & 7;
#pragma unroll
    for (int ks = 0; ks < 2; ++ks) {
        int off = ((ks * 4 + kgl) ^ xr) << 3;
        bf16x8 a[4], b[4];
#pragma unroll
        for (int i = 0; i < 4; ++i) {
            a[i] = lds_load8(&ldsA[(wr + i * 16 + lrow) * 64 + off]);
            b[i] = lds_load8(&ldsB[(wc + i * 16 + lrow) * 64 + off]);
        }
#pragma unroll
        for (int i = 0; i < 4; ++i)
#pragma unroll
            for (int j = 0; j < 4; ++j)
                acc[i][j] = __builtin_amdgcn_mfma_f32_16x16x32_bf16(a[i], b[j], acc[i][j], 0, 0, 0);
    }
}

// ---------------- kernel 1: prep = cast x (fp32->bf16) + transpose-cast W ----------------
__global__ __launch_bounds__(256) void prep_kernel(const float* __restrict__ x,
                                                   const float* __restrict__ wq,
                                                   const float* __restrict__ wk,
                                                   const float* __restrict__ wv,
                                                   u16* __restrict__ xb,
                                                   u16* __restrict__ wt) {
    __shared__ __align__(16) u16 tile[64][80];
    int blk = blockIdx.x;
    if (blk >= 768) {
        size_t g = (size_t)(blk - 768) * 256 + threadIdx.x;   // group of 4 elems
        f32x4 v = ((const f32x4*)x)[g];
        u16 o[4] = {f32_to_bf16(v.x), f32_to_bf16(v.y), f32_to_bf16(v.z), f32_to_bf16(v.w)};
        *(unsigned long long*)(xb + g * 4) = *(const unsigned long long*)o;
        return;
    }
    int z = blk >> 8;            // 0..2 : which W
    int rem = blk & 255;
    int kt = rem >> 4, nt2 = rem & 15;
    const float* w = z == 0 ? wq : (z == 1 ? wk : wv);
    int k0 = kt * 64, n0 = nt2 * 64;
    for (int g = threadIdx.x; g < 1024; g += 256) {
        int r = g >> 4, c = (g & 15) << 2;
        f32x4 v = *(const f32x4*)(w + (size_t)(k0 + r) * 1024 + n0 + c);
        tile[r][c + 0] = f32_to_bf16(v.x);
        tile[r][c + 1] = f32_to_bf16(v.y);
        tile[r][c + 2] = f32_to_bf16(v.z);
        tile[r][c + 3] = f32_to_bf16(v.w);
    }
    __syncthreads();
    u16* out = wt + (size_t)z * 1024 * 1024;
    for (int g = threadIdx.x; g < 512; g += 256) {
        int nr = g >> 3, kc = (g & 7) << 3;
        __align__(16) u16 tmp[8];
#pragma unroll
        for (int i = 0; i < 8; ++i) tmp[i] = tile[kc + i][nr];
        *(u32x4*)(out + (size_t)(n0 + nr) * 1024 + k0 + kc) = *(const u32x4*)tmp;
    }
}

// ---------------- kernel 2: QKV GEMM, XCD-localized work remap ----------------
// Linear grid 3072. Dispatch id d -> work w = (d&7)*384 + (d>>3): assuming
// round-robin id%8 -> XCD, each XCD owns 16 consecutive mt strips, so each
// xb A-strip is fetched into exactly one XCD's L2 (R4 FETCH 143 MB vs ~40 ideal).
__global__ __launch_bounds__(256, 4) void gemm_qkv_kernel(const u16* __restrict__ xb,
                                                          const u16* __restrict__ wt,
                                                          u16* __restrict__ qkv) {
    __shared__ __align__(16) u16 ldsA[128 * 64];
    __shared__ __align__(16) u16 ldsB[128 * 64];
    int d = blockIdx.x;
    int w = (d & 7) * 384 + (d >> 3);
    int mt = w / 24, nt = w % 24;
    const u16* A = xb + (size_t)mt * 128 * 1024;
    const u16* B = wt + (size_t)nt * 128 * 1024;
    int tid = threadIdx.x;
    f32x4 acc[4][4] = {};
    for (int kt = 0; kt < 16; ++kt) {
        __syncthreads();
        stage_tile64(A + kt * 64, 1024, ldsA, tid);
        stage_tile64(B + kt * 64, 1024, ldsB, tid);
        __syncthreads();
        mfma_step64(ldsA, ldsB, tid, acc);
    }
    int lane = tid & 63, wv = tid >> 6;
    int wr = (wv >> 1) * 64, wc = (wv & 1) * 64;
    int r0 = (lane >> 4) * 4, c0 = lane & 15;
    size_t mbase = (size_t)mt * 128;
    int nbase = nt * 128;
#pragma unroll
    for (int i = 0; i < 4; ++i)
#pragma unroll
        for (int j = 0; j < 4; ++j) {
            int col = nbase + wc + j * 16 + c0;
            float scale = (col < 1024) ? 0.03125f : 1.0f;  // fold 1/sqrt(1024) into Q
#pragma unroll
            for (int r = 0; r < 4; ++r) {
                int row = wr + i * 16 + r0 + r;
                qkv[(mbase + row) * (size_t)N_QKV + col] = f32_to_bf16(acc[i][j][r] * scale);
            }
        }
}

// ---------------- kernel 3: transpose V -> Vt [b][d][m] ----------------
__global__ __launch_bounds__(256) void transpose_v_kernel(const u16* __restrict__ qkv,
                                                          u16* __restrict__ vt) {
    __shared__ __align__(16) u16 tile[64][80];
    int m0 = blockIdx.x * 64, d0 = blockIdx.y * 64, b = blockIdx.z;
    const u16* src = qkv + (size_t)b * SEQ * N_QKV + 2048;  // V columns
    for (int g = threadIdx.x; g < 512; g += 256) {
        int r = g >> 3, c = (g & 7) << 3;
        *(u32x4*)&tile[r][c] = *(const u32x4*)(src + (size_t)(m0 + r) * N_QKV + d0 + c);
    }
    __syncthreads();
    u16* dst = vt + (size_t)b * DIM * SEQ;
    for (int g = threadIdx.x; g < 512; g += 256) {
        int dr = g >> 3, mc = (g & 7) << 3;
        __align__(16) u16 tmp[8];
#pragma unroll
        for (int i = 0; i < 8; ++i) tmp[i] = tile[mc + i][dr];
        *(u32x4*)(dst + (size_t)(d0 + dr) * SEQ + m0 + mc) = *(const u32x4*)tmp;
    }
}

// ---------------- kernel 4: S = Q . K^T, triangular grid, bf16 output ----------------
__global__ __launch_bounds__(256, 4) void gemm_scores_kernel(const u16* __restrict__ qkv,
                                                             u16* __restrict__ S) {
    int t = blockIdx.x;      // 0..135 triangular index
    int b = blockIdx.y;
    int ntile = (int)((sqrtf(8.0f * (float)t + 1.0f) - 1.0f) * 0.5f);
    while ((ntile + 1) * (ntile + 2) / 2 <= t) ++ntile;
    while (ntile * (ntile + 1) / 2 > t) --ntile;
    int mtile = t - ntile * (ntile + 1) / 2;   // 0 <= mtile <= ntile
    __shared__ __align__(16) u16 ldsA[128 * 64];
    __shared__ __align__(16) u16 ldsB[128 * 64];
    const u16* A = qkv + (size_t)b * SEQ * N_QKV + (size_t)ntile * 128 * N_QKV;        // Q rows
    const u16* B = qkv + (size_t)b * SEQ * N_QKV + (size_t)mtile * 128 * N_QKV + 1024; // K rows
    int tid = threadIdx.x;
    f32x4 acc[4][4] = {};
    for (int kt = 0; kt < 16; ++kt) {
        __syncthreads();
        stage_tile64(A + kt * 64, N_QKV, ldsA, tid);
        stage_tile64(B + kt * 64, N_QKV, ldsB, tid);
        __syncthreads();
        mfma_step64(ldsA, ldsB, tid, acc);
    }
    u16* out = S + (size_t)b * SEQ * SEQ + (size_t)ntile * 128 * SEQ + (size_t)mtile * 128;
    int lane = tid & 63, wv = tid >> 6;
    int wr = (wv >> 1) * 64, wc = (wv & 1) * 64;
    int r0 = (lane >> 4) * 4, c0 = lane & 15;
#pragma unroll
    for (int i = 0; i < 4; ++i)
#pragma unroll
        for (int j = 0; j < 4; ++j) {
            int col = wc + j * 16 + c0;
#pragma unroll
            for (int r = 0; r < 4; ++r) {
                int row = wr + i * 16 + r0 + r;
                out[(size_t)row * SEQ + col] = f32_to_bf16(acc[i][j][r]);
            }
        }
}

// ---------------- kernel 5: row softmax over bf16 S, in-place, register-resident ----
__global__ __launch_bounds__(256) void softmax_kernel(u16* __restrict__ SP) {
    int gr = blockIdx.x;
    int n = gr & 2047;
    u16* s = SP + (size_t)gr * SEQ;
    __shared__ float red[4];
    int t = threadIdx.x;
    int base = t << 3;
    int len = n + 1;
    float v[8];
    float lmax = -3.0e38f;
    if (base < len) {
        u32x4 raw = *(const u32x4*)(s + base);
        const u16* h = (const u16*)&raw;
#pragma unroll
        for (int i = 0; i < 8; ++i) {
            v[i] = (base + i < len) ? bf16_to_f32(h[i]) : -3.0e38f;
            lmax = fmaxf(lmax, v[i]);
        }
    } else {
#pragma unroll
        for (int i = 0; i < 8; ++i) v[i] = -3.0e38f;
    }
#pragma unroll
    for (int off = 32; off; off >>= 1) lmax = fmaxf(lmax, __shfl_xor(lmax, off, 64));
    if ((t & 63) == 0) red[t >> 6] = lmax;
    __syncthreads();
    float gmax = fmaxf(fmaxf(red[0], red[1]), fmaxf(red[2], red[3]));
    __syncthreads();   // everyone has gmax before red is reused
    float lsum = 0.f;
#pragma unroll
    for (int i = 0; i < 8; ++i) {
        float e = __expf(v[i] - gmax);   // masked lanes -> exp(-huge) = 0
        v[i] = e;
        lsum += e;
    }
#pragma unroll
    for (int off = 32; off; off >>= 1) lsum += __shfl_xor(lsum, off, 64);
    if ((t & 63) == 0) red[t >> 6] = lsum;
    __syncthreads();
    float inv = 1.0f / (red[0] + red[1] + red[2] + red[3]);
    __align__(16) u16 o[8];
#pragma unroll
    for (int i = 0; i < 8; ++i) o[i] = f32_to_bf16(v[i] * inv);  // masked lanes write 0
    *(u32x4*)(s + base) = *(const u32x4*)o;
}

// ---------------- kernel 6: O = P . V (via Vt), causal K truncation ----------------
// ntile reversed so the longest blocks (kTiles=32) dispatch first (tail balance).
__global__ __launch_bounds__(256, 4) void gemm_out_kernel(const u16* __restrict__ P,
                                                          const u16* __restrict__ vt,
                                                          float* __restrict__ O) {
    __shared__ __align__(16) u16 ldsA[128 * 64];
    __shared__ __align__(16) u16 ldsB[128 * 64];
    int dt = blockIdx.x, b = blockIdx.z;
    int ntile = (SEQ / 128 - 1) - blockIdx.y;
    const u16* A = P + (size_t)b * SEQ * SEQ + (size_t)ntile * 128 * SEQ;
    const u16* B = vt + (size_t)b * DIM * SEQ + (size_t)dt * 128 * SEQ;
    int tid = threadIdx.x;
    f32x4 acc[4][4] = {};
    int kTiles = ntile * 2 + 2;  // keys beyond n0+127 have P == 0 (BK=64 units)
    for (int kt = 0; kt < kTiles; ++kt) {
        __syncthreads();
        stage_tile64(A + kt * 64, SEQ, ldsA, tid);
        stage_tile64(B + kt * 64, SEQ, ldsB, tid);
        __syncthreads();
        mfma_step64(ldsA, ldsB, tid, acc);
    }
    float* out = O + (size_t)b * SEQ * DIM + (size_t)ntile * 128 * DIM + (size_t)dt * 128;
    int lane = tid & 63, wv = tid >> 6;
    int wr = (wv >> 1) * 64, wc = (wv & 1) * 64;
    int r0 = (lane >> 4) * 4, c0 = lane & 15;
#pragma unroll
    for (int i = 0; i < 4; ++i)
#pragma unroll
        for (int j = 0; j < 4; ++j) {
            int col = wc + j * 16 + c0;
#pragma unroll
            for (int r = 0; r < 4; ++r) {
                int row = wr + i * 16 + r0 + r;
                out[(size_t)row * DIM + col] = acc[i][j][r];
            }
        }
}

extern "C" void kernel_launch(void* const* d_in, const int* in_sizes, int n_in,
                              void* d_out, int out_size, void* d_ws, size_t ws_size,
                              hipStream_t stream) {
    const float* x = (const float*)d_in[0];
    const float* wq = (const float*)d_in[1];
    const float* wk = (const float*)d_in[2];
    const float* wv = (const float*)d_in[3];
    char* ws = (char*)d_ws;
    u16* qkv = (u16*)(ws + OFF_QKV);
    u16* vt = (u16*)(ws + OFF_VT);
    u16* xb = (u16*)(ws + OFF_XB);
    u16* wt = (u16*)(ws + OFF_WT);
    u16* S = (u16*)(ws + OFF_S);   // aliases xb/wt region (dead by then)
    float* O = (float*)d_out;

    prep_kernel<<<768 + M_TOT * DIM / 4 / 256, 256, 0, stream>>>(x, wq, wk, wv, xb, wt);
    gemm_qkv_kernel<<<N_QKV / 128 * (M_TOT / 128), 256, 0, stream>>>(xb, wt, qkv);
    transpose_v_kernel<<<dim3(SEQ / 64, DIM / 64, BATCH), 256, 0, stream>>>(qkv, vt);
    gemm_scores_kernel<<<dim3(136, BATCH), 256, 0, stream>>>(qkv, S);
    softmax_kernel<<<BATCH * SEQ, 256, 0, stream>>>(S);
    gemm_out_kernel<<<dim3(DIM / 128, SEQ / 128, BATCH), 256, 0, stream>>>(S, vt, O);
}